// Round 1
// baseline (494.383 us; speedup 1.0000x reference)
//
#include <hip/hip_runtime.h>
#include <math.h>

// Problem constants (fixed by the reference)
#define NQ_ED   256       // EMBED_DIM
#define NL      4
#define NH      8
#define NP      4
#define HD      32        // HEAD_DIM
#define HMAX    128
#define WMAX    128
#define NLP     16        // NL*NP
#define NC      128       // NL*NP*NH (attn cols)
#define QPB     4         // queries per block (amortize weight-matrix reads)

__global__ __launch_bounds__(256) void msda_fused_kernel(
    const float* __restrict__ query,      // (Q, 256)
    const float* __restrict__ refp,       // (Q, 2)
    const float* __restrict__ V,          // (B, 128, 128, 4, 256)
    const float* __restrict__ W_off,      // (256, 256)
    const float* __restrict__ b_off,      // (256,)
    const float* __restrict__ W_attn,     // (256, 128)
    const float* __restrict__ b_attn,     // (128,)
    const float* __restrict__ W_out,      // (256, 256)
    const float* __restrict__ b_out,      // (256,)
    const int*   __restrict__ batch_off,  // (n_batch,)
    int n_batch,
    const int*   __restrict__ spatial,    // (4, 2) [h, w]
    float* __restrict__ out)              // (Q, 256)
{
    __shared__ float q_s[QPB][NQ_ED];     // query rows; reused as out_pre rows
    __shared__ float off_s[QPB][NQ_ED];
    __shared__ float aw_s[QPB][NC];
    __shared__ int   sx0[QPB][NC], sx1[QPB][NC], sy0[QPB][NC], sy1[QPB][NC];
    __shared__ float swa[QPB][NC], swb[QPB][NC], swc[QPB][NC], swd[QPB][NC];

    const int t  = threadIdx.x;
    const int q0 = blockIdx.x * QPB;

    // ---- load query rows ----
    #pragma unroll
    for (int s = 0; s < QPB; ++s)
        q_s[s][t] = query[(size_t)(q0 + s) * NQ_ED + t];
    __syncthreads();

    // ---- GEMM phase: offsets (256 cols) + attn logits (128 cols) ----
    {
        float acc[QPB];
        #pragma unroll
        for (int s = 0; s < QPB; ++s) acc[s] = 0.f;
        for (int e = 0; e < NQ_ED; ++e) {
            float w = W_off[e * NQ_ED + t];
            #pragma unroll
            for (int s = 0; s < QPB; ++s) acc[s] += q_s[s][e] * w;
        }
        float bo = b_off[t];
        #pragma unroll
        for (int s = 0; s < QPB; ++s) off_s[s][t] = acc[s] + bo;

        if (t < NC) {
            float acc2[QPB];
            #pragma unroll
            for (int s = 0; s < QPB; ++s) acc2[s] = 0.f;
            for (int e = 0; e < NQ_ED; ++e) {
                float w = W_attn[e * NC + t];
                #pragma unroll
                for (int s = 0; s < QPB; ++s) acc2[s] += q_s[s][e] * w;
            }
            float ba = b_attn[t];
            #pragma unroll
            for (int s = 0; s < QPB; ++s) aw_s[s][t] = acc2[s] + ba;
        }
    }
    __syncthreads();

    // ---- softmax over the 16 (level,point) entries per (sub-query, head) ----
    if (t < QPB * NH) {
        int s = t >> 3, h = t & 7;
        float m = -1e30f;
        #pragma unroll
        for (int lp = 0; lp < NLP; ++lp) m = fmaxf(m, aw_s[s][lp * NH + h]);
        float ex[NLP], sum = 0.f;
        #pragma unroll
        for (int lp = 0; lp < NLP; ++lp) {
            float e = __expf(aw_s[s][lp * NH + h] - m);
            ex[lp] = e; sum += e;
        }
        float inv = 1.f / sum;
        #pragma unroll
        for (int lp = 0; lp < NLP; ++lp) aw_s[s][lp * NH + h] = ex[lp] * inv;
    }
    __syncthreads();

    // ---- sampling parameters: thread t<128 handles column c=t for all sub-queries ----
    if (t < NC) {
        const int c = t;
        const int l = c >> 5;                  // c / (NP*NH)
        const int hsz = spatial[l * 2 + 0];
        const int wsz = spatial[l * 2 + 1];
        const float hszf = (float)hsz, wszf = (float)wsz;
        const int wcap = wsz - 1, hcap = hsz - 1;
        #pragma unroll
        for (int s = 0; s < QPB; ++s) {
            const int qid = q0 + s;
            float rx = refp[qid * 2 + 0], ry = refp[qid * 2 + 1];
            rx = fminf(fmaxf(rx, 0.f), 1.f);
            ry = fminf(fmaxf(ry, 0.f), 1.f);
            float ivx = logf(fmaxf(rx, 1e-5f) / fmaxf(1.f - rx, 1e-5f));
            float ivy = logf(fmaxf(ry, 1e-5f) / fmaxf(1.f - ry, 1e-5f));
            float ox = off_s[s][c * 2 + 0], oy = off_s[s][c * 2 + 1];
            // loc = sigmoid(inv + off) * 2 - 1
            float lx = 2.f / (1.f + __expf(-(ivx + ox))) - 1.f;
            float ly = 2.f / (1.f + __expf(-(ivy + oy))) - 1.f;
            float x = ((lx + 1.f) * wszf - 1.f) * 0.5f;
            float y = ((ly + 1.f) * hszf - 1.f) * 0.5f;
            float fx0 = floorf(x), fy0 = floorf(y);
            int x0 = (int)fx0, y0 = (int)fy0;
            int x1 = x0 + 1,  y1 = y0 + 1;
            x0 = min(max(x0, 0), wcap); x1 = min(max(x1, 0), wcap);
            y0 = min(max(y0, 0), hcap); y1 = min(max(y1, 0), hcap);
            float x0f = (float)x0, x1f = (float)x1;
            float y0f = (float)y0, y1f = (float)y1;
            // weights computed from CLIPPED corner coords (matches reference)
            swa[s][c] = (x1f - x) * (y1f - y);
            swb[s][c] = (x1f - x) * (y - y0f);
            swc[s][c] = (x - x0f) * (y1f - y);
            swd[s][c] = (x - x0f) * (y - y0f);
            sx0[s][c] = x0; sx1[s][c] = x1;
            sy0[s][c] = y0; sy1[s][c] = y1;
        }
    }
    __syncthreads();

    // ---- bilinear gather + attention-weighted accumulate ----
    // thread t = h*32 + d; out_pre column = h*HD + d
    const int h = t >> 5, d = t & 31;
    float accg[QPB];
    #pragma unroll
    for (int s = 0; s < QPB; ++s) {
        const int qid = q0 + s;
        int b = 0;
        for (int i = 1; i < n_batch; ++i)
            if (batch_off[i] <= qid) b = i;
        const float* Vb = V + (size_t)b * HMAX * WMAX * NL * NQ_ED;
        float acc = 0.f;
        #pragma unroll
        for (int lp = 0; lp < NLP; ++lp) {
            const int c = lp * NH + h;
            const int l = lp >> 2;
            const int x0 = sx0[s][c], x1 = sx1[s][c];
            const int y0 = sy0[s][c], y1 = sy1[s][c];
            const float wa = swa[s][c], wb = swb[s][c];
            const float wc = swc[s][c], wd = swd[s][c];
            const float a  = aw_s[s][c];
            const int inner = l * NQ_ED + h * HD + d;
            // reference indexes V[b, x, y, l, h, d] (x on first spatial axis)
            const float* row0 = Vb + (size_t)x0 * (WMAX * NL * NQ_ED);
            const float* row1 = Vb + (size_t)x1 * (WMAX * NL * NQ_ED);
            float v00 = row0[(size_t)y0 * (NL * NQ_ED) + inner];
            float v01 = row0[(size_t)y1 * (NL * NQ_ED) + inner];
            float v10 = row1[(size_t)y0 * (NL * NQ_ED) + inner];
            float v11 = row1[(size_t)y1 * (NL * NQ_ED) + inner];
            acc += a * (wa * v00 + wb * v01 + wc * v10 + wd * v11);
        }
        accg[s] = acc;
    }
    __syncthreads();                 // q_s no longer needed; reuse for out_pre
    #pragma unroll
    for (int s = 0; s < QPB; ++s) q_s[s][t] = accg[s];
    __syncthreads();

    // ---- output GEMM: out = out_pre @ W_out + b_out ----
    {
        float acc[QPB];
        #pragma unroll
        for (int s = 0; s < QPB; ++s) acc[s] = 0.f;
        for (int e = 0; e < NQ_ED; ++e) {
            float w = W_out[e * NQ_ED + t];
            #pragma unroll
            for (int s = 0; s < QPB; ++s) acc[s] += q_s[s][e] * w;
        }
        float bo = b_out[t];
        #pragma unroll
        for (int s = 0; s < QPB; ++s)
            out[(size_t)(q0 + s) * NQ_ED + t] = acc[s] + bo;
    }
}

extern "C" void kernel_launch(void* const* d_in, const int* in_sizes, int n_in,
                              void* d_out, int out_size, void* d_ws, size_t ws_size,
                              hipStream_t stream) {
    const float* query  = (const float*)d_in[0];
    const float* refp   = (const float*)d_in[1];
    const float* V      = (const float*)d_in[2];
    const float* W_off  = (const float*)d_in[3];
    const float* b_off  = (const float*)d_in[4];
    const float* W_attn = (const float*)d_in[5];
    const float* b_attn = (const float*)d_in[6];
    const float* W_out  = (const float*)d_in[7];
    const float* b_out  = (const float*)d_in[8];
    const int*   boff   = (const int*)d_in[9];
    const int*   spat   = (const int*)d_in[10];
    const int n_batch   = in_sizes[9];
    const int nq        = in_sizes[0] / NQ_ED;

    float* out = (float*)d_out;
    dim3 grid(nq / QPB), block(256);
    msda_fused_kernel<<<grid, block, 0, stream>>>(
        query, refp, V, W_off, b_off, W_attn, b_attn, W_out, b_out,
        boff, n_batch, spat, out);
}

// Round 2
// 372.764 us; speedup vs baseline: 1.3263x; 1.3263x over previous
//
#include <hip/hip_runtime.h>
#include <math.h>

#define ED      256       // EMBED_DIM
#define NL      4
#define NH      8
#define NP      4
#define HD      32        // HEAD_DIM
#define HMAX    128
#define WMAX    128
#define NLP     16        // NL*NP
#define NC      128       // NL*NP*NH
#define QPB     4         // queries per block
#define BSTRIDE (HMAX*WMAX*NL*ED)   // 16,777,216 elements
#define XSTRIDE (WMAX*NL*ED)        // 131,072
#define YSTRIDE (NL*ED)             // 1,024

__global__ __launch_bounds__(256, 4) void msda_fused_kernel(
    const float* __restrict__ query,      // (Q, 256)
    const float* __restrict__ refp,       // (Q, 2)
    const float* __restrict__ V,          // (B, 128, 128, 4, 256)
    const float* __restrict__ W_off,      // (256, 256)
    const float* __restrict__ b_off,      // (256,)
    const float* __restrict__ W_attn,     // (256, 128)
    const float* __restrict__ b_attn,     // (128,)
    const float* __restrict__ W_out,      // (256, 256)
    const float* __restrict__ b_out,      // (256,)
    const int*   __restrict__ batch_off,  // (n_batch,)
    int n_batch,
    const int*   __restrict__ spatial,    // (4, 2) [h, w]
    float* __restrict__ out)              // (Q, 256)
{
    __shared__ float q_s[QPB][ED];      // query rows; later reused as out_pre
    __shared__ float off_s[QPB][ED];
    __shared__ float aw_s[QPB][NC];
    __shared__ int   soff[QPB][NC][4];  // corner element offsets (batch folded in)
    __shared__ float swt[QPB][NC][4];   // attention-premultiplied bilinear weights

    const int t  = threadIdx.x;
    const int q0 = blockIdx.x * QPB;

    // ---- load query rows (coalesced) ----
    #pragma unroll
    for (int s = 0; s < QPB; ++s)
        q_s[s][t] = query[(size_t)(q0 + s) * ED + t];
    __syncthreads();

    // ---- GEMM1: off = q @ W_off + b_off  (256 cols, float4 per thread) ----
    {
        const int s  = t >> 6;            // sub-query 0..3
        const int c4 = (t & 63) << 2;     // column group base
        float4 acc = {0.f, 0.f, 0.f, 0.f};
        const float4* Wp = (const float4*)W_off + (c4 >> 2);  // row stride = 64 float4
        for (int e = 0; e < ED; e += 4) {
            float4 qv = *(const float4*)&q_s[s][e];
            float4 w0 = Wp[(e + 0) * 64];
            float4 w1 = Wp[(e + 1) * 64];
            float4 w2 = Wp[(e + 2) * 64];
            float4 w3 = Wp[(e + 3) * 64];
            acc.x += qv.x*w0.x + qv.y*w1.x + qv.z*w2.x + qv.w*w3.x;
            acc.y += qv.x*w0.y + qv.y*w1.y + qv.z*w2.y + qv.w*w3.y;
            acc.z += qv.x*w0.z + qv.y*w1.z + qv.z*w2.z + qv.w*w3.z;
            acc.w += qv.x*w0.w + qv.y*w1.w + qv.z*w2.w + qv.w*w3.w;
        }
        float4 bo = *(const float4*)&b_off[c4];
        acc.x += bo.x; acc.y += bo.y; acc.z += bo.z; acc.w += bo.w;
        *(float4*)&off_s[s][c4] = acc;
    }

    // ---- GEMM2: attn logits = q @ W_attn + b_attn (128 cols) ----
    if (t < 128) {
        const int s  = t >> 5;
        const int c4 = (t & 31) << 2;
        float4 acc = {0.f, 0.f, 0.f, 0.f};
        const float4* Wp = (const float4*)W_attn + (c4 >> 2); // row stride = 32 float4
        for (int e = 0; e < ED; e += 4) {
            float4 qv = *(const float4*)&q_s[s][e];
            float4 w0 = Wp[(e + 0) * 32];
            float4 w1 = Wp[(e + 1) * 32];
            float4 w2 = Wp[(e + 2) * 32];
            float4 w3 = Wp[(e + 3) * 32];
            acc.x += qv.x*w0.x + qv.y*w1.x + qv.z*w2.x + qv.w*w3.x;
            acc.y += qv.x*w0.y + qv.y*w1.y + qv.z*w2.y + qv.w*w3.y;
            acc.z += qv.x*w0.z + qv.y*w1.z + qv.z*w2.z + qv.w*w3.z;
            acc.w += qv.x*w0.w + qv.y*w1.w + qv.z*w2.w + qv.w*w3.w;
        }
        float4 ba = *(const float4*)&b_attn[c4];
        acc.x += ba.x; acc.y += ba.y; acc.z += ba.z; acc.w += ba.w;
        *(float4*)&aw_s[s][c4] = acc;
    }
    __syncthreads();

    // ---- softmax over 16 (level,point) entries per (sub-query, head) ----
    if (t < QPB * NH) {
        int s = t >> 3, h = t & 7;
        float m = -1e30f;
        #pragma unroll
        for (int lp = 0; lp < NLP; ++lp) m = fmaxf(m, aw_s[s][lp * NH + h]);
        float ex[NLP], sum = 0.f;
        #pragma unroll
        for (int lp = 0; lp < NLP; ++lp) {
            float e = __expf(aw_s[s][lp * NH + h] - m);
            ex[lp] = e; sum += e;
        }
        float inv = 1.f / sum;
        #pragma unroll
        for (int lp = 0; lp < NLP; ++lp) aw_s[s][lp * NH + h] = ex[lp] * inv;
    }
    __syncthreads();

    // ---- sampling params: corner offsets + premultiplied weights ----
    if (t < NC) {
        const int c = t;
        const int l = c >> 5;
        const int hsz = spatial[l * 2 + 0];
        const int wsz = spatial[l * 2 + 1];
        const float hszf = (float)hsz, wszf = (float)wsz;
        const int wcap = wsz - 1, hcap = hsz - 1;
        #pragma unroll
        for (int s = 0; s < QPB; ++s) {
            const int qid = q0 + s;
            int b = 0;
            for (int i = 1; i < n_batch; ++i)
                if (batch_off[i] <= qid) b = i;
            const int bbase = b * BSTRIDE;

            float rx = refp[qid * 2 + 0], ry = refp[qid * 2 + 1];
            rx = fminf(fmaxf(rx, 0.f), 1.f);
            ry = fminf(fmaxf(ry, 0.f), 1.f);
            float ivx = __logf(fmaxf(rx, 1e-5f) / fmaxf(1.f - rx, 1e-5f));
            float ivy = __logf(fmaxf(ry, 1e-5f) / fmaxf(1.f - ry, 1e-5f));
            float ox = off_s[s][c * 2 + 0], oy = off_s[s][c * 2 + 1];
            float lx = 2.f / (1.f + __expf(-(ivx + ox))) - 1.f;
            float ly = 2.f / (1.f + __expf(-(ivy + oy))) - 1.f;
            float x = ((lx + 1.f) * wszf - 1.f) * 0.5f;
            float y = ((ly + 1.f) * hszf - 1.f) * 0.5f;
            int x0 = (int)floorf(x), y0 = (int)floorf(y);
            int x1 = x0 + 1,  y1 = y0 + 1;
            x0 = min(max(x0, 0), wcap); x1 = min(max(x1, 0), wcap);
            y0 = min(max(y0, 0), hcap); y1 = min(max(y1, 0), hcap);
            float x0f = (float)x0, x1f = (float)x1;
            float y0f = (float)y0, y1f = (float)y1;
            const float a = aw_s[s][c];
            // corner order: (x0,y0)=wa, (x0,y1)=wb, (x1,y0)=wc, (x1,y1)=wd
            swt[s][c][0] = a * (x1f - x) * (y1f - y);
            swt[s][c][1] = a * (x1f - x) * (y - y0f);
            swt[s][c][2] = a * (x - x0f) * (y1f - y);
            swt[s][c][3] = a * (x - x0f) * (y - y0f);
            const int lbase = bbase + l * ED;
            soff[s][c][0] = lbase + x0 * XSTRIDE + y0 * YSTRIDE;
            soff[s][c][1] = lbase + x0 * XSTRIDE + y1 * YSTRIDE;
            soff[s][c][2] = lbase + x1 * XSTRIDE + y0 * YSTRIDE;
            soff[s][c][3] = lbase + x1 * XSTRIDE + y1 * YSTRIDE;
        }
    }
    __syncthreads();

    // ---- gather: thread = (s, h, d4); float4 per corner ----
    {
        const int s   = t >> 6;
        const int rem = t & 63;
        const int h   = rem >> 3;
        const int d4  = (rem & 7) << 2;
        const int inner = h * HD + d4;
        float4 acc = {0.f, 0.f, 0.f, 0.f};
        #pragma unroll 4
        for (int lp = 0; lp < NLP; ++lp) {
            const int c = lp * NH + h;
            int4   o = *(const int4*)soff[s][c];
            float4 w = *(const float4*)swt[s][c];
            float4 v0 = *(const float4*)&V[o.x + inner];
            float4 v1 = *(const float4*)&V[o.y + inner];
            float4 v2 = *(const float4*)&V[o.z + inner];
            float4 v3 = *(const float4*)&V[o.w + inner];
            acc.x += w.x*v0.x + w.y*v1.x + w.z*v2.x + w.w*v3.x;
            acc.y += w.x*v0.y + w.y*v1.y + w.z*v2.y + w.w*v3.y;
            acc.z += w.x*v0.z + w.y*v1.z + w.z*v2.z + w.w*v3.z;
            acc.w += w.x*v0.w + w.y*v1.w + w.z*v2.w + w.w*v3.w;
        }
        __syncthreads();                 // q_s free now
        *(float4*)&q_s[s][inner] = acc;  // out_pre
    }
    __syncthreads();

    // ---- out GEMM: out = out_pre @ W_out + b_out ----
    {
        const int s  = t >> 6;
        const int c4 = (t & 63) << 2;
        float4 acc = {0.f, 0.f, 0.f, 0.f};
        const float4* Wp = (const float4*)W_out + (c4 >> 2);
        for (int e = 0; e < ED; e += 4) {
            float4 qv = *(const float4*)&q_s[s][e];
            float4 w0 = Wp[(e + 0) * 64];
            float4 w1 = Wp[(e + 1) * 64];
            float4 w2 = Wp[(e + 2) * 64];
            float4 w3 = Wp[(e + 3) * 64];
            acc.x += qv.x*w0.x + qv.y*w1.x + qv.z*w2.x + qv.w*w3.x;
            acc.y += qv.x*w0.y + qv.y*w1.y + qv.z*w2.y + qv.w*w3.y;
            acc.z += qv.x*w0.z + qv.y*w1.z + qv.z*w2.z + qv.w*w3.z;
            acc.w += qv.x*w0.w + qv.y*w1.w + qv.z*w2.w + qv.w*w3.w;
        }
        float4 bo = *(const float4*)&b_out[c4];
        acc.x += bo.x; acc.y += bo.y; acc.z += bo.z; acc.w += bo.w;
        *(float4*)&out[(size_t)(q0 + s) * ED + c4] = acc;
    }
}

extern "C" void kernel_launch(void* const* d_in, const int* in_sizes, int n_in,
                              void* d_out, int out_size, void* d_ws, size_t ws_size,
                              hipStream_t stream) {
    const float* query  = (const float*)d_in[0];
    const float* refp   = (const float*)d_in[1];
    const float* V      = (const float*)d_in[2];
    const float* W_off  = (const float*)d_in[3];
    const float* b_off  = (const float*)d_in[4];
    const float* W_attn = (const float*)d_in[5];
    const float* b_attn = (const float*)d_in[6];
    const float* W_out  = (const float*)d_in[7];
    const float* b_out  = (const float*)d_in[8];
    const int*   boff   = (const int*)d_in[9];
    const int*   spat   = (const int*)d_in[10];
    const int n_batch   = in_sizes[9];
    const int nq        = in_sizes[0] / ED;

    float* out = (float*)d_out;
    dim3 grid(nq / QPB), block(256);
    msda_fused_kernel<<<grid, block, 0, stream>>>(
        query, refp, V, W_off, b_off, W_attn, b_attn, W_out, b_out,
        boff, n_batch, spat, out);
}

// Round 4
// 290.124 us; speedup vs baseline: 1.7040x; 1.2848x over previous
//
#include <hip/hip_runtime.h>
#include <math.h>

#define ED      256       // EMBED_DIM
#define NL      4
#define NH      8
#define NP      4
#define HD      32        // HEAD_DIM
#define HMAX    128
#define WMAX    128
#define NLP     16        // NL*NP
#define NC      128       // NL*NP*NH
#define NOFF_AW 384       // 256 off cols + 128 attn cols
#define QPB     4         // queries per block in sampler
#define BSTRIDE (HMAX*WMAX*NL*ED)   // 16,777,216 elements
#define XSTRIDE (WMAX*NL*ED)        // 131,072
#define YSTRIDE (NL*ED)             // 1,024

typedef __attribute__((ext_vector_type(8))) short bf16x8;
typedef __attribute__((ext_vector_type(4))) float f32x4;

__device__ __forceinline__ unsigned short f2bf(float x) {
    unsigned int u = __float_as_uint(x);
    u = (u + 0x7fffu + ((u >> 16) & 1u)) >> 16;   // RNE
    return (unsigned short)u;
}
__device__ __forceinline__ float bf2f(unsigned short h) {
    unsigned int u = ((unsigned int)h) << 16;
    return __uint_as_float(u);
}

// ---------------- K0: conversions (hi/lo split) + weight transposes -------
// qh/ql: (nq,256)  q = qh + ql  (bf16 pair, ~fp32 precision)
// BTh/BTl: (384,256) transposed [W_off | W_attn], hi/lo split
// WoutT: (256,256) transposed W_out, plain bf16
__global__ __launch_bounds__(256) void msda_convert_kernel(
    const float* __restrict__ query,
    const float* __restrict__ W_off,
    const float* __restrict__ W_attn,
    const float* __restrict__ W_out,
    unsigned short* __restrict__ qh,
    unsigned short* __restrict__ ql,
    unsigned short* __restrict__ BTh,
    unsigned short* __restrict__ BTl,
    unsigned short* __restrict__ WoutT,
    int nq)
{
    const int idx = blockIdx.x * 256 + threadIdx.x;
    const int t1 = nq * ED;
    const int t2 = NOFF_AW * ED;
    const int t3 = ED * ED;
    if (idx < t1) {
        float v = query[idx];
        unsigned short h = f2bf(v);
        qh[idx] = h;
        ql[idx] = f2bf(v - bf2f(h));
    } else if (idx < t1 + t2) {
        int i = idx - t1;
        int c = i >> 8, e = i & 255;
        float v = (c < ED) ? W_off[e * ED + c] : W_attn[e * NC + (c - ED)];
        unsigned short h = f2bf(v);
        BTh[i] = h;
        BTl[i] = f2bf(v - bf2f(h));
    } else if (idx < t1 + t2 + t3) {
        int i = idx - t1 - t2;
        int c = i >> 8, e = i & 255;
        WoutT[i] = f2bf(W_out[e * ED + c]);
    }
}

// ------- K1: split-precision MFMA GEMM: C = (Ah+Al) @ (Bh+Bl)^T + bias ----
// Accumulates Ah@Bh + Al@Bh + Ah@Bl  (drops Al@Bl ~ 2^-18 relative).
// Per-wave tile: 16 rows x 64 cols, K=256 in 8 steps of 32.
__global__ __launch_bounds__(256) void gemm_split_kernel(
    const unsigned short* __restrict__ Ah,
    const unsigned short* __restrict__ Al,
    const unsigned short* __restrict__ BTh,
    const unsigned short* __restrict__ BTl,
    const float* __restrict__ bias0,
    const float* __restrict__ bias1,
    float* __restrict__ C,
    int M, int NTOT, int bias_split)
{
    const int wave = threadIdx.x >> 6;
    const int lane = threadIdx.x & 63;
    const int gw   = blockIdx.x * 4 + wave;
    const int ngroups = NTOT >> 6;
    const int mg = gw / ngroups, ng = gw % ngroups;
    const int m16 = mg * 16, n64 = ng * 64;
    if (m16 >= M) return;

    const int mrow = lane & 15;
    const int quad = lane >> 4;

    const bf16x8* Ahp = (const bf16x8*)(Ah + (size_t)(m16 + mrow) * 256 + quad * 8);
    const bf16x8* Alp = (const bf16x8*)(Al + (size_t)(m16 + mrow) * 256 + quad * 8);
    const bf16x8* Bh0 = (const bf16x8*)(BTh + (size_t)(n64 +  0 + mrow) * 256 + quad * 8);
    const bf16x8* Bh1 = (const bf16x8*)(BTh + (size_t)(n64 + 16 + mrow) * 256 + quad * 8);
    const bf16x8* Bh2 = (const bf16x8*)(BTh + (size_t)(n64 + 32 + mrow) * 256 + quad * 8);
    const bf16x8* Bh3 = (const bf16x8*)(BTh + (size_t)(n64 + 48 + mrow) * 256 + quad * 8);
    const bf16x8* Bl0 = (const bf16x8*)(BTl + (size_t)(n64 +  0 + mrow) * 256 + quad * 8);
    const bf16x8* Bl1 = (const bf16x8*)(BTl + (size_t)(n64 + 16 + mrow) * 256 + quad * 8);
    const bf16x8* Bl2 = (const bf16x8*)(BTl + (size_t)(n64 + 32 + mrow) * 256 + quad * 8);
    const bf16x8* Bl3 = (const bf16x8*)(BTl + (size_t)(n64 + 48 + mrow) * 256 + quad * 8);

    f32x4 acc0 = {0.f,0.f,0.f,0.f}, acc1 = acc0, acc2 = acc0, acc3 = acc0;
    #pragma unroll
    for (int kb = 0; kb < 8; ++kb) {
        bf16x8 ah = Ahp[kb * 4];
        bf16x8 al = Alp[kb * 4];
        bf16x8 b0 = Bh0[kb * 4], b1 = Bh1[kb * 4], b2 = Bh2[kb * 4], b3 = Bh3[kb * 4];
        acc0 = __builtin_amdgcn_mfma_f32_16x16x32_bf16(ah, b0, acc0, 0, 0, 0);
        acc1 = __builtin_amdgcn_mfma_f32_16x16x32_bf16(ah, b1, acc1, 0, 0, 0);
        acc2 = __builtin_amdgcn_mfma_f32_16x16x32_bf16(ah, b2, acc2, 0, 0, 0);
        acc3 = __builtin_amdgcn_mfma_f32_16x16x32_bf16(ah, b3, acc3, 0, 0, 0);
        acc0 = __builtin_amdgcn_mfma_f32_16x16x32_bf16(al, b0, acc0, 0, 0, 0);
        acc1 = __builtin_amdgcn_mfma_f32_16x16x32_bf16(al, b1, acc1, 0, 0, 0);
        acc2 = __builtin_amdgcn_mfma_f32_16x16x32_bf16(al, b2, acc2, 0, 0, 0);
        acc3 = __builtin_amdgcn_mfma_f32_16x16x32_bf16(al, b3, acc3, 0, 0, 0);
        acc0 = __builtin_amdgcn_mfma_f32_16x16x32_bf16(ah, Bl0[kb * 4], acc0, 0, 0, 0);
        acc1 = __builtin_amdgcn_mfma_f32_16x16x32_bf16(ah, Bl1[kb * 4], acc1, 0, 0, 0);
        acc2 = __builtin_amdgcn_mfma_f32_16x16x32_bf16(ah, Bl2[kb * 4], acc2, 0, 0, 0);
        acc3 = __builtin_amdgcn_mfma_f32_16x16x32_bf16(ah, Bl3[kb * 4], acc3, 0, 0, 0);
    }

    const int col = lane & 15;
    f32x4 accs[4] = {acc0, acc1, acc2, acc3};
    #pragma unroll
    for (int i = 0; i < 4; ++i) {
        int n = n64 + i * 16 + col;
        float b = (n < bias_split) ? bias0[n] : bias1[n - bias_split];
        #pragma unroll
        for (int r = 0; r < 4; ++r) {
            int row = m16 + quad * 4 + r;
            C[(size_t)row * NTOT + n] = accs[i][r] + b;
        }
    }
}

// ---------------- plain bf16 MFMA GEMM (for K3) ---------------------------
__global__ __launch_bounds__(256) void gemm_bf16_kernel(
    const unsigned short* __restrict__ A,
    const unsigned short* __restrict__ BT,
    const float* __restrict__ bias,
    float* __restrict__ C,
    int M, int NTOT)
{
    const int wave = threadIdx.x >> 6;
    const int lane = threadIdx.x & 63;
    const int gw   = blockIdx.x * 4 + wave;
    const int ngroups = NTOT >> 6;
    const int mg = gw / ngroups, ng = gw % ngroups;
    const int m16 = mg * 16, n64 = ng * 64;
    if (m16 >= M) return;

    const int mrow = lane & 15;
    const int quad = lane >> 4;

    const bf16x8* Arow = (const bf16x8*)(A + (size_t)(m16 + mrow) * 256 + quad * 8);
    const bf16x8* B0 = (const bf16x8*)(BT + (size_t)(n64 +  0 + mrow) * 256 + quad * 8);
    const bf16x8* B1 = (const bf16x8*)(BT + (size_t)(n64 + 16 + mrow) * 256 + quad * 8);
    const bf16x8* B2 = (const bf16x8*)(BT + (size_t)(n64 + 32 + mrow) * 256 + quad * 8);
    const bf16x8* B3 = (const bf16x8*)(BT + (size_t)(n64 + 48 + mrow) * 256 + quad * 8);

    f32x4 acc0 = {0.f,0.f,0.f,0.f}, acc1 = acc0, acc2 = acc0, acc3 = acc0;
    #pragma unroll
    for (int kb = 0; kb < 8; ++kb) {
        bf16x8 af = Arow[kb * 4];
        acc0 = __builtin_amdgcn_mfma_f32_16x16x32_bf16(af, B0[kb * 4], acc0, 0, 0, 0);
        acc1 = __builtin_amdgcn_mfma_f32_16x16x32_bf16(af, B1[kb * 4], acc1, 0, 0, 0);
        acc2 = __builtin_amdgcn_mfma_f32_16x16x32_bf16(af, B2[kb * 4], acc2, 0, 0, 0);
        acc3 = __builtin_amdgcn_mfma_f32_16x16x32_bf16(af, B3[kb * 4], acc3, 0, 0, 0);
    }

    const int col = lane & 15;
    f32x4 accs[4] = {acc0, acc1, acc2, acc3};
    #pragma unroll
    for (int i = 0; i < 4; ++i) {
        int n = n64 + i * 16 + col;
        float b = bias[n];
        #pragma unroll
        for (int r = 0; r < 4; ++r) {
            int row = m16 + quad * 4 + r;
            C[(size_t)row * NTOT + n] = accs[i][r] + b;
        }
    }
}

// ---------------- K2: softmax + sampling + bilinear gather ----------------
__global__ __launch_bounds__(256) void msda_sample_kernel(
    const float* __restrict__ refp,       // (Q, 2)
    const float* __restrict__ V,          // (B, 128, 128, 4, 256)
    const float* __restrict__ off_aw,     // (Q, 384): [0:256)=off, [256:384)=aw logits
    const int*   __restrict__ batch_off,
    int n_batch,
    const int*   __restrict__ spatial,    // (4,2)
    unsigned short* __restrict__ out_pre, // (Q, 256) bf16
    int q_total)
{
    __shared__ float  law[QPB][NC];
    __shared__ float2 sminv[QPB][NH];
    __shared__ float2 sref[QPB];
    __shared__ int4   soff[QPB][NC];
    __shared__ float4 swt[QPB][NC];

    const int t  = threadIdx.x;
    const int q0 = blockIdx.x * QPB;

    // ---- load attn logits ----
    {
        const int s = t >> 6, c = t & 63;
        const float* row = off_aw + (size_t)(q0 + s) * NOFF_AW + ED;
        law[s][c]      = row[c];
        law[s][c + 64] = row[c + 64];
    }
    __syncthreads();

    // ---- softmax stats + ref-point prep ----
    if (t < QPB * NH) {
        const int s = t >> 3, h = t & 7;
        float m = -1e30f;
        #pragma unroll
        for (int lp = 0; lp < NLP; ++lp) m = fmaxf(m, law[s][lp * NH + h]);
        float sum = 0.f;
        #pragma unroll
        for (int lp = 0; lp < NLP; ++lp) sum += __expf(law[s][lp * NH + h] - m);
        sminv[s][h] = make_float2(m, 1.f / sum);
    } else if (t < QPB * NH + QPB) {
        const int s = t - QPB * NH;
        const int qid = q0 + s;
        float rx = refp[qid * 2 + 0], ry = refp[qid * 2 + 1];
        rx = fminf(fmaxf(rx, 0.f), 1.f);
        ry = fminf(fmaxf(ry, 0.f), 1.f);
        float ivx = __logf(fmaxf(rx, 1e-5f) / fmaxf(1.f - rx, 1e-5f));
        float ivy = __logf(fmaxf(ry, 1e-5f) / fmaxf(1.f - ry, 1e-5f));
        sref[s] = make_float2(ivx, ivy);
    }
    __syncthreads();

    // ---- sampling params: each thread handles c and c+64 ----
    {
        const int s = t >> 6;
        const int qid = q0 + s;
        int b = 0;
        for (int i = 1; i < n_batch; ++i)
            if (batch_off[i] <= qid) b = i;
        const int bbase = b * BSTRIDE;
        const float2 iv = sref[s];
        const float* offrow = off_aw + (size_t)qid * NOFF_AW;

        #pragma unroll
        for (int half = 0; half < 2; ++half) {
            const int c = (t & 63) + half * 64;
            const int l = c >> 5;
            const int h = c & 7;
            const int hsz = spatial[l * 2 + 0];
            const int wsz = spatial[l * 2 + 1];
            const int wcap = wsz - 1, hcap = hsz - 1;

            const float2 mi = sminv[s][h];
            const float a = __expf(law[s][c] - mi.x) * mi.y;

            const float ox = offrow[c * 2 + 0], oy = offrow[c * 2 + 1];
            float lx = 2.f / (1.f + __expf(-(iv.x + ox))) - 1.f;
            float ly = 2.f / (1.f + __expf(-(iv.y + oy))) - 1.f;
            float x = ((lx + 1.f) * (float)wsz - 1.f) * 0.5f;
            float y = ((ly + 1.f) * (float)hsz - 1.f) * 0.5f;
            int x0 = (int)floorf(x), y0 = (int)floorf(y);
            int x1 = x0 + 1, y1 = y0 + 1;
            x0 = min(max(x0, 0), wcap); x1 = min(max(x1, 0), wcap);
            y0 = min(max(y0, 0), hcap); y1 = min(max(y1, 0), hcap);
            float x0f = (float)x0, x1f = (float)x1;
            float y0f = (float)y0, y1f = (float)y1;

            float4 w;
            w.x = a * (x1f - x) * (y1f - y);
            w.y = a * (x1f - x) * (y - y0f);
            w.z = a * (x - x0f) * (y1f - y);
            w.w = a * (x - x0f) * (y - y0f);
            swt[s][c] = w;
            const int lbase = bbase + l * ED;
            int4 o;
            o.x = lbase + x0 * XSTRIDE + y0 * YSTRIDE;
            o.y = lbase + x0 * XSTRIDE + y1 * YSTRIDE;
            o.z = lbase + x1 * XSTRIDE + y0 * YSTRIDE;
            o.w = lbase + x1 * XSTRIDE + y1 * YSTRIDE;
            soff[s][c] = o;
        }
    }
    __syncthreads();

    // ---- gather: one wave per query; lane = (h, d4) ----
    {
        const int s    = t >> 6;
        const int lane = t & 63;
        const int h    = lane >> 3;
        const int d4   = (lane & 7) << 2;
        const int inner = h * HD + d4;
        float4 acc = {0.f, 0.f, 0.f, 0.f};
        #pragma unroll 4
        for (int lp = 0; lp < NLP; ++lp) {
            const int c = lp * NH + h;
            int4   o = soff[s][c];
            float4 w = swt[s][c];
            float4 v0 = *(const float4*)&V[o.x + inner];
            float4 v1 = *(const float4*)&V[o.y + inner];
            float4 v2 = *(const float4*)&V[o.z + inner];
            float4 v3 = *(const float4*)&V[o.w + inner];
            acc.x += w.x*v0.x + w.y*v1.x + w.z*v2.x + w.w*v3.x;
            acc.y += w.x*v0.y + w.y*v1.y + w.z*v2.y + w.w*v3.y;
            acc.z += w.x*v0.z + w.y*v1.z + w.z*v2.z + w.w*v3.z;
            acc.w += w.x*v0.w + w.y*v1.w + w.z*v2.w + w.w*v3.w;
        }
        ushort4 o4;
        o4.x = f2bf(acc.x); o4.y = f2bf(acc.y);
        o4.z = f2bf(acc.z); o4.w = f2bf(acc.w);
        *(ushort4*)&out_pre[(size_t)(q0 + s) * ED + inner] = o4;
    }
}

extern "C" void kernel_launch(void* const* d_in, const int* in_sizes, int n_in,
                              void* d_out, int out_size, void* d_ws, size_t ws_size,
                              hipStream_t stream) {
    const float* query  = (const float*)d_in[0];
    const float* refp   = (const float*)d_in[1];
    const float* V      = (const float*)d_in[2];
    const float* W_off  = (const float*)d_in[3];
    const float* b_off  = (const float*)d_in[4];
    const float* W_attn = (const float*)d_in[5];
    const float* b_attn = (const float*)d_in[6];
    const float* W_out  = (const float*)d_in[7];
    const float* b_out  = (const float*)d_in[8];
    const int*   boff   = (const int*)d_in[9];
    const int*   spat   = (const int*)d_in[10];
    const int n_batch   = in_sizes[9];
    const int nq        = in_sizes[0] / ED;
    float* out = (float*)d_out;

    // workspace layout
    char* ws = (char*)d_ws;
    float*          off_aw  = (float*)ws;                                   // nq*384 f32
    unsigned short* qh      = (unsigned short*)(ws + (size_t)nq*NOFF_AW*4); // nq*256
    unsigned short* ql      = qh    + (size_t)nq*ED;                        // nq*256
    unsigned short* BTh     = ql    + (size_t)nq*ED;                        // 384*256
    unsigned short* BTl     = BTh   + NOFF_AW*ED;                           // 384*256
    unsigned short* WoutT   = BTl   + NOFF_AW*ED;                           // 256*256
    unsigned short* out_pre = WoutT + ED*ED;                                // nq*256

    // K0: conversions
    {
        int total = nq*ED + NOFF_AW*ED + ED*ED;
        msda_convert_kernel<<<(total + 255)/256, 256, 0, stream>>>(
            query, W_off, W_attn, W_out, qh, ql, BTh, BTl, WoutT, nq);
    }
    // K1: [off|aw] = q @ [W_off|W_attn] + bias (split precision)
    {
        int waves = (nq/16) * (NOFF_AW/64);
        gemm_split_kernel<<<(waves + 3)/4, 256, 0, stream>>>(
            qh, ql, BTh, BTl, b_off, b_attn, off_aw, nq, NOFF_AW, ED);
    }
    // K2: sampling + gather -> out_pre (bf16)
    {
        msda_sample_kernel<<<nq/QPB, 256, 0, stream>>>(
            refp, V, off_aw, boff, n_batch, spat, out_pre, nq);
    }
    // K3: out = out_pre @ W_out + b_out
    {
        int waves = (nq/16) * (ED/64);
        gemm_bf16_kernel<<<(waves + 3)/4, 256, 0, stream>>>(
            out_pre, WoutT, b_out, out, nq, ED);
    }
}

// Round 5
// 274.767 us; speedup vs baseline: 1.7993x; 1.0559x over previous
//
#include <hip/hip_runtime.h>
#include <math.h>

#define ED      256       // EMBED_DIM
#define NL      4
#define NH      8
#define NP      4
#define HD      32        // HEAD_DIM
#define HMAX    128
#define WMAX    128
#define NLP     16        // NL*NP
#define NC      128       // NL*NP*NH
#define NOFF_AW 384       // 256 off cols + 128 attn cols
#define QPB     4         // queries per block in sampler
#define BSTRIDE (HMAX*WMAX*NL*ED)   // 16,777,216 elements
#define XSTRIDE (WMAX*NL*ED)        // 131,072
#define YSTRIDE (NL*ED)             // 1,024

typedef __attribute__((ext_vector_type(8))) short    bf16x8;
typedef __attribute__((ext_vector_type(8))) __fp16   f16x8;
typedef __attribute__((ext_vector_type(4))) float    f32x4;

__device__ __forceinline__ unsigned short f2bf(float x) {
    unsigned int u = __float_as_uint(x);
    u = (u + 0x7fffu + ((u >> 16) & 1u)) >> 16;   // RNE
    return (unsigned short)u;
}

// ---------------- K0: weight conversion/transpose only -------------------
// WcatT_f16[c][e] = f16(c<256 ? W_off[e][c] : W_attn[e][c-256])  (384x256)
// WoutT_bf[c][e]  = bf16(W_out[e][c])                            (256x256)
__global__ __launch_bounds__(256) void msda_wconv_kernel(
    const float* __restrict__ W_off,
    const float* __restrict__ W_attn,
    const float* __restrict__ W_out,
    __fp16*         __restrict__ WcatT,
    unsigned short* __restrict__ WoutT)
{
    const int idx = blockIdx.x * 256 + threadIdx.x;
    const int t2 = NOFF_AW * ED;
    const int t3 = ED * ED;
    if (idx < t2) {
        int c = idx >> 8, e = idx & 255;
        float v = (c < ED) ? W_off[e * ED + c] : W_attn[e * NC + (c - ED)];
        WcatT[idx] = (__fp16)v;
    } else if (idx < t2 + t3) {
        int i = idx - t2;
        int c = i >> 8, e = i & 255;
        WoutT[i] = f2bf(W_out[e * ED + c]);
    }
}

// ------- K1: f16 2-pass MFMA GEMM: C = (Ah+Al) @ Bh^T + bias --------------
// A is f32; Ah/Al split computed in-register (A exact to 2^-22).
// Only B's f16 quantization error remains. Per-wave tile 16x64, K=256.
__global__ __launch_bounds__(256) void gemm_f16_kernel(
    const float*  __restrict__ A,     // (M,256) f32
    const __fp16* __restrict__ BT,    // (NTOT,256) f16 (B transposed)
    const float* __restrict__ bias0,
    const float* __restrict__ bias1,
    float* __restrict__ C,
    int M, int NTOT, int bias_split)
{
    const int wave = threadIdx.x >> 6;
    const int lane = threadIdx.x & 63;
    const int gw   = blockIdx.x * 4 + wave;
    const int ngroups = NTOT >> 6;
    const int mg = gw / ngroups, ng = gw % ngroups;
    const int m16 = mg * 16, n64 = ng * 64;
    if (m16 >= M) return;

    const int mrow = lane & 15;
    const int quad = lane >> 4;

    const float4* Arow = (const float4*)(A + (size_t)(m16 + mrow) * 256 + quad * 8);
    const f16x8* B0 = (const f16x8*)(BT + (size_t)(n64 +  0 + mrow) * 256 + quad * 8);
    const f16x8* B1 = (const f16x8*)(BT + (size_t)(n64 + 16 + mrow) * 256 + quad * 8);
    const f16x8* B2 = (const f16x8*)(BT + (size_t)(n64 + 32 + mrow) * 256 + quad * 8);
    const f16x8* B3 = (const f16x8*)(BT + (size_t)(n64 + 48 + mrow) * 256 + quad * 8);

    f32x4 acc0 = {0.f,0.f,0.f,0.f}, acc1 = acc0, acc2 = acc0, acc3 = acc0;
    #pragma unroll
    for (int kb = 0; kb < 8; ++kb) {
        float4 a0 = Arow[kb * 8 + 0];
        float4 a1 = Arow[kb * 8 + 1];
        float av[8] = {a0.x, a0.y, a0.z, a0.w, a1.x, a1.y, a1.z, a1.w};
        f16x8 ah, al;
        #pragma unroll
        for (int j = 0; j < 8; ++j) {
            __fp16 h = (__fp16)av[j];
            ah[j] = h;
            al[j] = (__fp16)(av[j] - (float)h);
        }
        f16x8 b0 = B0[kb * 4], b1 = B1[kb * 4], b2 = B2[kb * 4], b3 = B3[kb * 4];
        acc0 = __builtin_amdgcn_mfma_f32_16x16x32_f16(ah, b0, acc0, 0, 0, 0);
        acc1 = __builtin_amdgcn_mfma_f32_16x16x32_f16(ah, b1, acc1, 0, 0, 0);
        acc2 = __builtin_amdgcn_mfma_f32_16x16x32_f16(ah, b2, acc2, 0, 0, 0);
        acc3 = __builtin_amdgcn_mfma_f32_16x16x32_f16(ah, b3, acc3, 0, 0, 0);
        acc0 = __builtin_amdgcn_mfma_f32_16x16x32_f16(al, b0, acc0, 0, 0, 0);
        acc1 = __builtin_amdgcn_mfma_f32_16x16x32_f16(al, b1, acc1, 0, 0, 0);
        acc2 = __builtin_amdgcn_mfma_f32_16x16x32_f16(al, b2, acc2, 0, 0, 0);
        acc3 = __builtin_amdgcn_mfma_f32_16x16x32_f16(al, b3, acc3, 0, 0, 0);
    }

    const int col = lane & 15;
    f32x4 accs[4] = {acc0, acc1, acc2, acc3};
    #pragma unroll
    for (int i = 0; i < 4; ++i) {
        int n = n64 + i * 16 + col;
        float b = (n < bias_split) ? bias0[n] : bias1[n - bias_split];
        #pragma unroll
        for (int r = 0; r < 4; ++r) {
            int row = m16 + quad * 4 + r;
            C[(size_t)row * NTOT + n] = accs[i][r] + b;
        }
    }
}

// ---------------- plain bf16 MFMA GEMM (K3) -------------------------------
__global__ __launch_bounds__(256) void gemm_bf16_kernel(
    const unsigned short* __restrict__ A,
    const unsigned short* __restrict__ BT,
    const float* __restrict__ bias,
    float* __restrict__ C,
    int M, int NTOT)
{
    const int wave = threadIdx.x >> 6;
    const int lane = threadIdx.x & 63;
    const int gw   = blockIdx.x * 4 + wave;
    const int ngroups = NTOT >> 6;
    const int mg = gw / ngroups, ng = gw % ngroups;
    const int m16 = mg * 16, n64 = ng * 64;
    if (m16 >= M) return;

    const int mrow = lane & 15;
    const int quad = lane >> 4;

    const bf16x8* Arow = (const bf16x8*)(A + (size_t)(m16 + mrow) * 256 + quad * 8);
    const bf16x8* B0 = (const bf16x8*)(BT + (size_t)(n64 +  0 + mrow) * 256 + quad * 8);
    const bf16x8* B1 = (const bf16x8*)(BT + (size_t)(n64 + 16 + mrow) * 256 + quad * 8);
    const bf16x8* B2 = (const bf16x8*)(BT + (size_t)(n64 + 32 + mrow) * 256 + quad * 8);
    const bf16x8* B3 = (const bf16x8*)(BT + (size_t)(n64 + 48 + mrow) * 256 + quad * 8);

    f32x4 acc0 = {0.f,0.f,0.f,0.f}, acc1 = acc0, acc2 = acc0, acc3 = acc0;
    #pragma unroll
    for (int kb = 0; kb < 8; ++kb) {
        bf16x8 af = Arow[kb * 4];
        acc0 = __builtin_amdgcn_mfma_f32_16x16x32_bf16(af, B0[kb * 4], acc0, 0, 0, 0);
        acc1 = __builtin_amdgcn_mfma_f32_16x16x32_bf16(af, B1[kb * 4], acc1, 0, 0, 0);
        acc2 = __builtin_amdgcn_mfma_f32_16x16x32_bf16(af, B2[kb * 4], acc2, 0, 0, 0);
        acc3 = __builtin_amdgcn_mfma_f32_16x16x32_bf16(af, B3[kb * 4], acc3, 0, 0, 0);
    }

    const int col = lane & 15;
    f32x4 accs[4] = {acc0, acc1, acc2, acc3};
    #pragma unroll
    for (int i = 0; i < 4; ++i) {
        int n = n64 + i * 16 + col;
        float b = bias[n];
        #pragma unroll
        for (int r = 0; r < 4; ++r) {
            int row = m16 + quad * 4 + r;
            C[(size_t)row * NTOT + n] = accs[i][r] + b;
        }
    }
}

// ---------------- K2: softmax + sampling + bilinear gather ----------------
__global__ __launch_bounds__(256) void msda_sample_kernel(
    const float* __restrict__ refp,       // (Q, 2)
    const float* __restrict__ V,          // (B, 128, 128, 4, 256)
    const float* __restrict__ off_aw,     // (Q, 384): [0:256)=off, [256:384)=aw logits
    const int*   __restrict__ batch_off,
    int n_batch,
    const int*   __restrict__ spatial,    // (4,2)
    unsigned short* __restrict__ out_pre, // (Q, 256) bf16
    int q_total)
{
    __shared__ float  law[QPB][NC];
    __shared__ float2 sminv[QPB][NH];
    __shared__ float2 sref[QPB];
    __shared__ int4   soff[QPB][NC];
    __shared__ float4 swt[QPB][NC];

    const int t  = threadIdx.x;
    const int q0 = blockIdx.x * QPB;

    // ---- load attn logits ----
    {
        const int s = t >> 6, c = t & 63;
        const float* row = off_aw + (size_t)(q0 + s) * NOFF_AW + ED;
        law[s][c]      = row[c];
        law[s][c + 64] = row[c + 64];
    }
    __syncthreads();

    // ---- softmax stats + ref-point prep ----
    if (t < QPB * NH) {
        const int s = t >> 3, h = t & 7;
        float m = -1e30f;
        #pragma unroll
        for (int lp = 0; lp < NLP; ++lp) m = fmaxf(m, law[s][lp * NH + h]);
        float sum = 0.f;
        #pragma unroll
        for (int lp = 0; lp < NLP; ++lp) sum += __expf(law[s][lp * NH + h] - m);
        sminv[s][h] = make_float2(m, 1.f / sum);
    } else if (t < QPB * NH + QPB) {
        const int s = t - QPB * NH;
        const int qid = q0 + s;
        float rx = refp[qid * 2 + 0], ry = refp[qid * 2 + 1];
        rx = fminf(fmaxf(rx, 0.f), 1.f);
        ry = fminf(fmaxf(ry, 0.f), 1.f);
        float ivx = __logf(fmaxf(rx, 1e-5f) / fmaxf(1.f - rx, 1e-5f));
        float ivy = __logf(fmaxf(ry, 1e-5f) / fmaxf(1.f - ry, 1e-5f));
        sref[s] = make_float2(ivx, ivy);
    }
    __syncthreads();

    // ---- sampling params: each thread handles c and c+64 ----
    {
        const int s = t >> 6;
        const int qid = q0 + s;
        int b = 0;
        for (int i = 1; i < n_batch; ++i)
            if (batch_off[i] <= qid) b = i;
        const int bbase = b * BSTRIDE;
        const float2 iv = sref[s];
        const float* offrow = off_aw + (size_t)qid * NOFF_AW;

        #pragma unroll
        for (int half = 0; half < 2; ++half) {
            const int c = (t & 63) + half * 64;
            const int l = c >> 5;
            const int h = c & 7;
            const int hsz = spatial[l * 2 + 0];
            const int wsz = spatial[l * 2 + 1];
            const int wcap = wsz - 1, hcap = hsz - 1;

            const float2 mi = sminv[s][h];
            const float a = __expf(law[s][c] - mi.x) * mi.y;

            const float ox = offrow[c * 2 + 0], oy = offrow[c * 2 + 1];
            float lx = 2.f / (1.f + __expf(-(iv.x + ox))) - 1.f;
            float ly = 2.f / (1.f + __expf(-(iv.y + oy))) - 1.f;
            float x = ((lx + 1.f) * (float)wsz - 1.f) * 0.5f;
            float y = ((ly + 1.f) * (float)hsz - 1.f) * 0.5f;
            int x0 = (int)floorf(x), y0 = (int)floorf(y);
            int x1 = x0 + 1, y1 = y0 + 1;
            x0 = min(max(x0, 0), wcap); x1 = min(max(x1, 0), wcap);
            y0 = min(max(y0, 0), hcap); y1 = min(max(y1, 0), hcap);
            float x0f = (float)x0, x1f = (float)x1;
            float y0f = (float)y0, y1f = (float)y1;

            float4 w;
            w.x = a * (x1f - x) * (y1f - y);
            w.y = a * (x1f - x) * (y - y0f);
            w.z = a * (x - x0f) * (y1f - y);
            w.w = a * (x - x0f) * (y - y0f);
            swt[s][c] = w;
            const int lbase = bbase + l * ED;
            int4 o;
            o.x = lbase + x0 * XSTRIDE + y0 * YSTRIDE;
            o.y = lbase + x0 * XSTRIDE + y1 * YSTRIDE;
            o.z = lbase + x1 * XSTRIDE + y0 * YSTRIDE;
            o.w = lbase + x1 * XSTRIDE + y1 * YSTRIDE;
            soff[s][c] = o;
        }
    }
    __syncthreads();

    // ---- gather: one wave per query; lane = (h, d4) ----
    {
        const int s    = t >> 6;
        const int lane = t & 63;
        const int h    = lane >> 3;
        const int d4   = (lane & 7) << 2;
        const int inner = h * HD + d4;
        float4 acc = {0.f, 0.f, 0.f, 0.f};
        #pragma unroll 4
        for (int lp = 0; lp < NLP; ++lp) {
            const int c = lp * NH + h;
            int4   o = soff[s][c];
            float4 w = swt[s][c];
            float4 v0 = *(const float4*)&V[o.x + inner];
            float4 v1 = *(const float4*)&V[o.y + inner];
            float4 v2 = *(const float4*)&V[o.z + inner];
            float4 v3 = *(const float4*)&V[o.w + inner];
            acc.x += w.x*v0.x + w.y*v1.x + w.z*v2.x + w.w*v3.x;
            acc.y += w.x*v0.y + w.y*v1.y + w.z*v2.y + w.w*v3.y;
            acc.z += w.x*v0.z + w.y*v1.z + w.z*v2.z + w.w*v3.z;
            acc.w += w.x*v0.w + w.y*v1.w + w.z*v2.w + w.w*v3.w;
        }
        ushort4 o4;
        o4.x = f2bf(acc.x); o4.y = f2bf(acc.y);
        o4.z = f2bf(acc.z); o4.w = f2bf(acc.w);
        *(ushort4*)&out_pre[(size_t)(q0 + s) * ED + inner] = o4;
    }
}

extern "C" void kernel_launch(void* const* d_in, const int* in_sizes, int n_in,
                              void* d_out, int out_size, void* d_ws, size_t ws_size,
                              hipStream_t stream) {
    const float* query  = (const float*)d_in[0];
    const float* refp   = (const float*)d_in[1];
    const float* V      = (const float*)d_in[2];
    const float* W_off  = (const float*)d_in[3];
    const float* b_off  = (const float*)d_in[4];
    const float* W_attn = (const float*)d_in[5];
    const float* b_attn = (const float*)d_in[6];
    const float* W_out  = (const float*)d_in[7];
    const float* b_out  = (const float*)d_in[8];
    const int*   boff   = (const int*)d_in[9];
    const int*   spat   = (const int*)d_in[10];
    const int n_batch   = in_sizes[9];
    const int nq        = in_sizes[0] / ED;
    float* out = (float*)d_out;

    // workspace layout
    char* ws = (char*)d_ws;
    float*          off_aw  = (float*)ws;                                    // nq*384 f32
    __fp16*         WcatT   = (__fp16*)(ws + (size_t)nq*NOFF_AW*4);          // 384*256 f16
    unsigned short* WoutT   = (unsigned short*)(WcatT + NOFF_AW*ED);         // 256*256 bf16
    unsigned short* out_pre = WoutT + ED*ED;                                 // nq*256 bf16

    // K0: weight conversions/transposes
    {
        int total = NOFF_AW*ED + ED*ED;
        msda_wconv_kernel<<<(total + 255)/256, 256, 0, stream>>>(
            W_off, W_attn, W_out, WcatT, WoutT);
    }
    // K1: [off|aw] = q @ [W_off|W_attn] + bias  (f16 2-pass, A exact)
    {
        int waves = (nq/16) * (NOFF_AW/64);
        gemm_f16_kernel<<<(waves + 3)/4, 256, 0, stream>>>(
            query, WcatT, b_off, b_attn, off_aw, nq, NOFF_AW, ED);
    }
    // K2: sampling + gather -> out_pre (bf16)
    {
        msda_sample_kernel<<<nq/QPB, 256, 0, stream>>>(
            refp, V, off_aw, boff, n_batch, spat, out_pre, nq);
    }
    // K3: out = out_pre @ W_out + b_out
    {
        int waves = (nq/16) * (ED/64);
        gemm_bf16_kernel<<<(waves + 3)/4, 256, 0, stream>>>(
            out_pre, WoutT, b_out, out, nq, ED);
    }
}

// Round 6
// 270.310 us; speedup vs baseline: 1.8289x; 1.0165x over previous
//
#include <hip/hip_runtime.h>
#include <math.h>

#define ED      256       // EMBED_DIM
#define NL      4
#define NH      8
#define NP      4
#define HD      32        // HEAD_DIM
#define HMAX    128
#define WMAX    128
#define NLP     16        // NL*NP
#define NC      128       // NL*NP*NH
#define NOFF_AW 384       // 256 off cols + 128 attn cols
#define QPB     4         // queries per block in sampler
#define NBK     1024      // sort buckets: batch(<=4) x 16 x 16
#define BSTRIDE (HMAX*WMAX*NL*ED)   // 16,777,216 elements
#define XSTRIDE (WMAX*NL*ED)        // 131,072
#define YSTRIDE (NL*ED)             // 1,024

typedef __attribute__((ext_vector_type(8))) __fp16   f16x8;
typedef __attribute__((ext_vector_type(4))) __fp16   f16x4;
typedef __attribute__((ext_vector_type(4))) float    f32x4;

// ---------------- Ksort: bucket queries by (batch, ref-point 16x16 tile) --
// Single block, 1024 threads. perm[] = query ids grouped by bucket.
__global__ __launch_bounds__(1024) void msda_sort_kernel(
    const float* __restrict__ refp,
    const int*   __restrict__ batch_off,
    int n_batch,
    int* __restrict__ bucket_of,   // (nq) scratch
    int* __restrict__ perm,        // (nq)
    int nq)
{
    __shared__ int cnt[NBK];
    __shared__ int scan[NBK];
    const int t = threadIdx.x;
    cnt[t] = 0;
    __syncthreads();

    const int iters = (nq + 1023) >> 10;
    for (int i = 0; i < iters; ++i) {
        int q = i * 1024 + t;
        if (q < nq) {
            int b = 0;
            for (int j = 1; j < n_batch; ++j)
                if (batch_off[j] <= q) b = j;
            b = min(b, 3);
            float rx = refp[q * 2 + 0], ry = refp[q * 2 + 1];
            int bx = min(15, max(0, (int)(rx * 16.f)));
            int by = min(15, max(0, (int)(ry * 16.f)));
            int bk = (b << 8) | (by << 4) | bx;
            bucket_of[q] = bk;
            atomicAdd(&cnt[bk], 1);
        }
    }
    __syncthreads();

    // exclusive prefix sum over NBK
    scan[t] = cnt[t];
    __syncthreads();
    for (int d = 1; d < NBK; d <<= 1) {
        int v = scan[t];
        int u = (t >= d) ? scan[t - d] : 0;
        __syncthreads();
        scan[t] = v + u;
        __syncthreads();
    }
    cnt[t] = scan[t] - cnt[t];   // exclusive start -> cursor
    __syncthreads();

    for (int i = 0; i < iters; ++i) {
        int q = i * 1024 + t;
        if (q < nq) {
            int bk = bucket_of[q];
            int pos = atomicAdd(&cnt[bk], 1);
            perm[pos] = q;
        }
    }
}

// ---------------- K0: weight conversion/transpose (all f16) ---------------
// WcatT[c][e] = f16(c<256 ? W_off[e][c] : W_attn[e][c-256])  (384x256)
// WoutT[c][e] = f16(W_out[e][c])                              (256x256)
__global__ __launch_bounds__(256) void msda_wconv_kernel(
    const float* __restrict__ W_off,
    const float* __restrict__ W_attn,
    const float* __restrict__ W_out,
    __fp16* __restrict__ WcatT,
    __fp16* __restrict__ WoutT)
{
    const int idx = blockIdx.x * 256 + threadIdx.x;
    const int t2 = NOFF_AW * ED;
    const int t3 = ED * ED;
    if (idx < t2) {
        int c = idx >> 8, e = idx & 255;
        float v = (c < ED) ? W_off[e * ED + c] : W_attn[e * NC + (c - ED)];
        WcatT[idx] = (__fp16)v;
    } else if (idx < t2 + t3) {
        int i = idx - t2;
        int c = i >> 8, e = i & 255;
        WoutT[i] = (__fp16)W_out[e * ED + c];
    }
}

// ------- K1: f16 2-pass MFMA GEMM: C = (Ah+Al) @ Bh^T + bias --------------
// A f32; Ah/Al split in-register (A exact to 2^-22); only B f16 error.
__global__ __launch_bounds__(256) void gemm_f16_kernel(
    const float*  __restrict__ A,     // (M,256) f32
    const __fp16* __restrict__ BT,    // (NTOT,256) f16
    const float* __restrict__ bias0,
    const float* __restrict__ bias1,
    float* __restrict__ C,
    int M, int NTOT, int bias_split)
{
    const int wave = threadIdx.x >> 6;
    const int lane = threadIdx.x & 63;
    const int gw   = blockIdx.x * 4 + wave;
    const int ngroups = NTOT >> 6;
    const int mg = gw / ngroups, ng = gw % ngroups;
    const int m16 = mg * 16, n64 = ng * 64;
    if (m16 >= M) return;

    const int mrow = lane & 15;
    const int quad = lane >> 4;

    const float4* Arow = (const float4*)(A + (size_t)(m16 + mrow) * 256 + quad * 8);
    const f16x8* B0 = (const f16x8*)(BT + (size_t)(n64 +  0 + mrow) * 256 + quad * 8);
    const f16x8* B1 = (const f16x8*)(BT + (size_t)(n64 + 16 + mrow) * 256 + quad * 8);
    const f16x8* B2 = (const f16x8*)(BT + (size_t)(n64 + 32 + mrow) * 256 + quad * 8);
    const f16x8* B3 = (const f16x8*)(BT + (size_t)(n64 + 48 + mrow) * 256 + quad * 8);

    f32x4 acc0 = {0.f,0.f,0.f,0.f}, acc1 = acc0, acc2 = acc0, acc3 = acc0;
    #pragma unroll
    for (int kb = 0; kb < 8; ++kb) {
        float4 a0 = Arow[kb * 8 + 0];
        float4 a1 = Arow[kb * 8 + 1];
        float av[8] = {a0.x, a0.y, a0.z, a0.w, a1.x, a1.y, a1.z, a1.w};
        f16x8 ah, al;
        #pragma unroll
        for (int j = 0; j < 8; ++j) {
            __fp16 h = (__fp16)av[j];
            ah[j] = h;
            al[j] = (__fp16)(av[j] - (float)h);
        }
        f16x8 b0 = B0[kb * 4], b1 = B1[kb * 4], b2 = B2[kb * 4], b3 = B3[kb * 4];
        acc0 = __builtin_amdgcn_mfma_f32_16x16x32_f16(ah, b0, acc0, 0, 0, 0);
        acc1 = __builtin_amdgcn_mfma_f32_16x16x32_f16(ah, b1, acc1, 0, 0, 0);
        acc2 = __builtin_amdgcn_mfma_f32_16x16x32_f16(ah, b2, acc2, 0, 0, 0);
        acc3 = __builtin_amdgcn_mfma_f32_16x16x32_f16(ah, b3, acc3, 0, 0, 0);
        acc0 = __builtin_amdgcn_mfma_f32_16x16x32_f16(al, b0, acc0, 0, 0, 0);
        acc1 = __builtin_amdgcn_mfma_f32_16x16x32_f16(al, b1, acc1, 0, 0, 0);
        acc2 = __builtin_amdgcn_mfma_f32_16x16x32_f16(al, b2, acc2, 0, 0, 0);
        acc3 = __builtin_amdgcn_mfma_f32_16x16x32_f16(al, b3, acc3, 0, 0, 0);
    }

    const int col = lane & 15;
    f32x4 accs[4] = {acc0, acc1, acc2, acc3};
    #pragma unroll
    for (int i = 0; i < 4; ++i) {
        int n = n64 + i * 16 + col;
        float b = (n < bias_split) ? bias0[n] : bias1[n - bias_split];
        #pragma unroll
        for (int r = 0; r < 4; ++r) {
            int row = m16 + quad * 4 + r;
            C[(size_t)row * NTOT + n] = accs[i][r] + b;
        }
    }
}

// ---------------- K3: plain f16 MFMA GEMM (A and B both f16) --------------
__global__ __launch_bounds__(256) void gemm_ff16_kernel(
    const __fp16* __restrict__ A,     // (M,256) f16
    const __fp16* __restrict__ BT,    // (NTOT,256) f16
    const float* __restrict__ bias,
    float* __restrict__ C,
    int M, int NTOT)
{
    const int wave = threadIdx.x >> 6;
    const int lane = threadIdx.x & 63;
    const int gw   = blockIdx.x * 4 + wave;
    const int ngroups = NTOT >> 6;
    const int mg = gw / ngroups, ng = gw % ngroups;
    const int m16 = mg * 16, n64 = ng * 64;
    if (m16 >= M) return;

    const int mrow = lane & 15;
    const int quad = lane >> 4;

    const f16x8* Arow = (const f16x8*)(A + (size_t)(m16 + mrow) * 256 + quad * 8);
    const f16x8* B0 = (const f16x8*)(BT + (size_t)(n64 +  0 + mrow) * 256 + quad * 8);
    const f16x8* B1 = (const f16x8*)(BT + (size_t)(n64 + 16 + mrow) * 256 + quad * 8);
    const f16x8* B2 = (const f16x8*)(BT + (size_t)(n64 + 32 + mrow) * 256 + quad * 8);
    const f16x8* B3 = (const f16x8*)(BT + (size_t)(n64 + 48 + mrow) * 256 + quad * 8);

    f32x4 acc0 = {0.f,0.f,0.f,0.f}, acc1 = acc0, acc2 = acc0, acc3 = acc0;
    #pragma unroll
    for (int kb = 0; kb < 8; ++kb) {
        f16x8 af = Arow[kb * 4];
        acc0 = __builtin_amdgcn_mfma_f32_16x16x32_f16(af, B0[kb * 4], acc0, 0, 0, 0);
        acc1 = __builtin_amdgcn_mfma_f32_16x16x32_f16(af, B1[kb * 4], acc1, 0, 0, 0);
        acc2 = __builtin_amdgcn_mfma_f32_16x16x32_f16(af, B2[kb * 4], acc2, 0, 0, 0);
        acc3 = __builtin_amdgcn_mfma_f32_16x16x32_f16(af, B3[kb * 4], acc3, 0, 0, 0);
    }

    const int col = lane & 15;
    f32x4 accs[4] = {acc0, acc1, acc2, acc3};
    #pragma unroll
    for (int i = 0; i < 4; ++i) {
        int n = n64 + i * 16 + col;
        float b = bias[n];
        #pragma unroll
        for (int r = 0; r < 4; ++r) {
            int row = m16 + quad * 4 + r;
            C[(size_t)row * NTOT + n] = accs[i][r] + b;
        }
    }
}

// ---------------- K2: softmax + sampling + bilinear gather (permuted) -----
__global__ __launch_bounds__(256) void msda_sample_kernel(
    const float* __restrict__ refp,       // (Q, 2)
    const float* __restrict__ V,          // (B, 128, 128, 4, 256)
    const float* __restrict__ off_aw,     // (Q, 384): [0:256)=off, [256:384)=aw logits
    const int*   __restrict__ perm,       // (Q) locality-sorted query ids
    const int*   __restrict__ batch_off,
    int n_batch,
    const int*   __restrict__ spatial,    // (4,2)
    __fp16* __restrict__ out_pre,         // (Q, 256) f16
    int q_total)
{
    __shared__ int    sqid[QPB];
    __shared__ float  law[QPB][NC];
    __shared__ float2 sminv[QPB][NH];
    __shared__ float2 sref[QPB];
    __shared__ int4   soff[QPB][NC];
    __shared__ float4 swt[QPB][NC];

    const int t = threadIdx.x;
    // XCD-chunk swizzle: each XCD (blockIdx % 8) gets a contiguous chunk of
    // sorted queries -> per-XCD L2 sees a compact V region.
    const int chunk = gridDim.x >> 3;
    const int pblk  = (blockIdx.x & 7) * chunk + (blockIdx.x >> 3);
    const int q0 = pblk * QPB;

    if (t < QPB) sqid[t] = perm[q0 + t];
    __syncthreads();

    // ---- load attn logits ----
    {
        const int s = t >> 6, c = t & 63;
        const float* row = off_aw + (size_t)sqid[s] * NOFF_AW + ED;
        law[s][c]      = row[c];
        law[s][c + 64] = row[c + 64];
    }
    __syncthreads();

    // ---- softmax stats + ref-point prep ----
    if (t < QPB * NH) {
        const int s = t >> 3, h = t & 7;
        float m = -1e30f;
        #pragma unroll
        for (int lp = 0; lp < NLP; ++lp) m = fmaxf(m, law[s][lp * NH + h]);
        float sum = 0.f;
        #pragma unroll
        for (int lp = 0; lp < NLP; ++lp) sum += __expf(law[s][lp * NH + h] - m);
        sminv[s][h] = make_float2(m, 1.f / sum);
    } else if (t < QPB * NH + QPB) {
        const int s = t - QPB * NH;
        const int qid = sqid[s];
        float rx = refp[qid * 2 + 0], ry = refp[qid * 2 + 1];
        rx = fminf(fmaxf(rx, 0.f), 1.f);
        ry = fminf(fmaxf(ry, 0.f), 1.f);
        float ivx = __logf(fmaxf(rx, 1e-5f) / fmaxf(1.f - rx, 1e-5f));
        float ivy = __logf(fmaxf(ry, 1e-5f) / fmaxf(1.f - ry, 1e-5f));
        sref[s] = make_float2(ivx, ivy);
    }
    __syncthreads();

    // ---- sampling params: each thread handles c and c+64 ----
    {
        const int s = t >> 6;
        const int qid = sqid[s];
        int b = 0;
        for (int i = 1; i < n_batch; ++i)
            if (batch_off[i] <= qid) b = i;
        const int bbase = b * BSTRIDE;
        const float2 iv = sref[s];
        const float* offrow = off_aw + (size_t)qid * NOFF_AW;

        #pragma unroll
        for (int half = 0; half < 2; ++half) {
            const int c = (t & 63) + half * 64;
            const int l = c >> 5;
            const int h = c & 7;
            const int hsz = spatial[l * 2 + 0];
            const int wsz = spatial[l * 2 + 1];
            const int wcap = wsz - 1, hcap = hsz - 1;

            const float2 mi = sminv[s][h];
            const float a = __expf(law[s][c] - mi.x) * mi.y;

            const float ox = offrow[c * 2 + 0], oy = offrow[c * 2 + 1];
            float lx = 2.f / (1.f + __expf(-(iv.x + ox))) - 1.f;
            float ly = 2.f / (1.f + __expf(-(iv.y + oy))) - 1.f;
            float x = ((lx + 1.f) * (float)wsz - 1.f) * 0.5f;
            float y = ((ly + 1.f) * (float)hsz - 1.f) * 0.5f;
            int x0 = (int)floorf(x), y0 = (int)floorf(y);
            int x1 = x0 + 1, y1 = y0 + 1;
            x0 = min(max(x0, 0), wcap); x1 = min(max(x1, 0), wcap);
            y0 = min(max(y0, 0), hcap); y1 = min(max(y1, 0), hcap);
            float x0f = (float)x0, x1f = (float)x1;
            float y0f = (float)y0, y1f = (float)y1;

            float4 w;
            w.x = a * (x1f - x) * (y1f - y);
            w.y = a * (x1f - x) * (y - y0f);
            w.z = a * (x - x0f) * (y1f - y);
            w.w = a * (x - x0f) * (y - y0f);
            swt[s][c] = w;
            const int lbase = bbase + l * ED;
            int4 o;
            o.x = lbase + x0 * XSTRIDE + y0 * YSTRIDE;
            o.y = lbase + x0 * XSTRIDE + y1 * YSTRIDE;
            o.z = lbase + x1 * XSTRIDE + y0 * YSTRIDE;
            o.w = lbase + x1 * XSTRIDE + y1 * YSTRIDE;
            soff[s][c] = o;
        }
    }
    __syncthreads();

    // ---- gather: one wave per query; lane = (h, d4) ----
    {
        const int s    = t >> 6;
        const int lane = t & 63;
        const int h    = lane >> 3;
        const int d4   = (lane & 7) << 2;
        const int inner = h * HD + d4;
        float4 acc = {0.f, 0.f, 0.f, 0.f};
        #pragma unroll 4
        for (int lp = 0; lp < NLP; ++lp) {
            const int c = lp * NH + h;
            int4   o = soff[s][c];
            float4 w = swt[s][c];
            float4 v0 = *(const float4*)&V[o.x + inner];
            float4 v1 = *(const float4*)&V[o.y + inner];
            float4 v2 = *(const float4*)&V[o.z + inner];
            float4 v3 = *(const float4*)&V[o.w + inner];
            acc.x += w.x*v0.x + w.y*v1.x + w.z*v2.x + w.w*v3.x;
            acc.y += w.x*v0.y + w.y*v1.y + w.z*v2.y + w.w*v3.y;
            acc.z += w.x*v0.z + w.y*v1.z + w.z*v2.z + w.w*v3.z;
            acc.w += w.x*v0.w + w.y*v1.w + w.z*v2.w + w.w*v3.w;
        }
        f16x4 o4;
        o4[0] = (__fp16)acc.x; o4[1] = (__fp16)acc.y;
        o4[2] = (__fp16)acc.z; o4[3] = (__fp16)acc.w;
        *(f16x4*)&out_pre[(size_t)sqid[s] * ED + inner] = o4;
    }
}

extern "C" void kernel_launch(void* const* d_in, const int* in_sizes, int n_in,
                              void* d_out, int out_size, void* d_ws, size_t ws_size,
                              hipStream_t stream) {
    const float* query  = (const float*)d_in[0];
    const float* refp   = (const float*)d_in[1];
    const float* V      = (const float*)d_in[2];
    const float* W_off  = (const float*)d_in[3];
    const float* b_off  = (const float*)d_in[4];
    const float* W_attn = (const float*)d_in[5];
    const float* b_attn = (const float*)d_in[6];
    const float* W_out  = (const float*)d_in[7];
    const float* b_out  = (const float*)d_in[8];
    const int*   boff   = (const int*)d_in[9];
    const int*   spat   = (const int*)d_in[10];
    const int n_batch   = in_sizes[9];
    const int nq        = in_sizes[0] / ED;
    float* out = (float*)d_out;

    // workspace layout
    char* ws = (char*)d_ws;
    float*   off_aw    = (float*)ws;                             // nq*384 f32
    int*     perm      = (int*)(off_aw + (size_t)nq * NOFF_AW);  // nq int
    int*     bucket_of = perm + nq;                              // nq int
    __fp16*  WcatT     = (__fp16*)(bucket_of + nq);              // 384*256 f16
    __fp16*  WoutT     = WcatT + NOFF_AW * ED;                   // 256*256 f16
    __fp16*  out_pre   = WoutT + ED * ED;                        // nq*256 f16

    // Ksort: locality permutation of queries
    msda_sort_kernel<<<1, 1024, 0, stream>>>(refp, boff, n_batch,
                                             bucket_of, perm, nq);
    // K0: weight conversions/transposes
    {
        int total = NOFF_AW * ED + ED * ED;
        msda_wconv_kernel<<<(total + 255) / 256, 256, 0, stream>>>(
            W_off, W_attn, W_out, WcatT, WoutT);
    }
    // K1: [off|aw] = q @ [W_off|W_attn] + bias  (f16 2-pass, A exact)
    {
        int waves = (nq / 16) * (NOFF_AW / 64);
        gemm_f16_kernel<<<(waves + 3) / 4, 256, 0, stream>>>(
            query, WcatT, b_off, b_attn, off_aw, nq, NOFF_AW, ED);
    }
    // K2: sampling + gather -> out_pre (f16), locality-sorted
    {
        msda_sample_kernel<<<nq / QPB, 256, 0, stream>>>(
            refp, V, off_aw, perm, boff, n_batch, spat, out_pre, nq);
    }
    // K3: out = out_pre @ W_out + b_out
    {
        int waves = (nq / 16) * (ED / 64);
        gemm_ff16_kernel<<<(waves + 3) / 4, 256, 0, stream>>>(
            out_pre, WoutT, b_out, out, nq, ED);
    }
}

// Round 7
// 266.421 us; speedup vs baseline: 1.8556x; 1.0146x over previous
//
#include <hip/hip_runtime.h>
#include <math.h>

#define ED      256       // EMBED_DIM
#define NL      4
#define NH      8
#define NP      4
#define HD      32        // HEAD_DIM
#define HMAX    128
#define WMAX    128
#define NLP     16        // NL*NP
#define NC      128       // NL*NP*NH
#define NOFF_AW 384       // 256 off cols + 128 attn cols
#define QPB     4         // queries per block in sampler
#define NBK     1024      // sort buckets
#define BSTRIDE (HMAX*WMAX*NL*ED)   // 16,777,216 elements
#define XSTRIDE (WMAX*NL*ED)        // 131,072
#define YSTRIDE (NL*ED)             // 1,024
#define RPB     21760               // compact rows per batch: 128^2+64^2+32^2+16^2
#define PBC     (RPB*256)           // compact elems per batch

typedef __attribute__((ext_vector_type(8))) __fp16   f16x8;
typedef __attribute__((ext_vector_type(4))) __fp16   f16x4;
typedef __attribute__((ext_vector_type(4))) float    f32x4;

__constant__ int LBASE_ROW[4] = {0, 16384, 20480, 21504};

// ---------------- Kprep: V compaction (f32->f16, drop masked zeros) -------
//                + weight transpose/convert + query locality sort ----------
// Vc[b][lbase + xi*sz + yi][e] = f16(V[b, xi, yi, l, e]),  sz = 128>>l
__global__ __launch_bounds__(1024) void msda_prep_kernel(
    const float* __restrict__ V,
    const float* __restrict__ W_off,
    const float* __restrict__ W_attn,
    const float* __restrict__ W_out,
    const float* __restrict__ refp,
    const int*   __restrict__ batch_off,
    int n_batch,
    __fp16* __restrict__ Vc,
    __fp16* __restrict__ WcatT,
    __fp16* __restrict__ WoutT,
    int* __restrict__ bucket_of,
    int* __restrict__ perm,
    int nq, int nb, int nCompact, int nWconv)
{
    __shared__ int cnt[NBK];
    __shared__ int scan[NBK];
    const int bid = blockIdx.x;
    const int t   = threadIdx.x;

    if (bid < nCompact) {
        // ---- V compaction: 16 rows/block, 64 lanes/row, float4 each ----
        const int r    = bid * 16 + (t >> 6);
        const int lane = t & 63;
        const int e    = lane << 2;
        const int total_rows = nb * RPB;
        if (r < total_rows) {
            const int b  = r / RPB;
            const int rr = r - b * RPB;
            int l, base;
            if (rr < 16384)      { l = 0; base = 0; }
            else if (rr < 20480) { l = 1; base = 16384; }
            else if (rr < 21504) { l = 2; base = 20480; }
            else                 { l = 3; base = 21504; }
            const int pos = rr - base;
            const int lsh = 7 - l;
            const int xi  = pos >> lsh;
            const int yi  = pos & ((1 << lsh) - 1);
            const float4 src = *(const float4*)&V[(size_t)b * BSTRIDE +
                (size_t)xi * XSTRIDE + (size_t)yi * YSTRIDE + l * ED + e];
            f16x4 d;
            d[0] = (__fp16)src.x; d[1] = (__fp16)src.y;
            d[2] = (__fp16)src.z; d[3] = (__fp16)src.w;
            *(f16x4*)&Vc[(size_t)r * 256 + e] = d;
        }
    } else if (bid < nCompact + nWconv) {
        // ---- weight transpose + f16 convert ----
        const int idx = (bid - nCompact) * 1024 + t;
        const int t2 = NOFF_AW * ED;
        const int t3 = ED * ED;
        if (idx < t2) {
            int c = idx >> 8, e = idx & 255;
            float v = (c < ED) ? W_off[e * ED + c] : W_attn[e * NC + (c - ED)];
            WcatT[idx] = (__fp16)v;
        } else if (idx < t2 + t3) {
            int i = idx - t2;
            int c = i >> 8, e = i & 255;
            WoutT[i] = (__fp16)W_out[e * ED + c];
        }
    } else {
        // ---- locality sort: bucket by (batch, 16x16 ref tile) ----
        cnt[t] = 0;
        __syncthreads();
        const int iters = (nq + 1023) >> 10;
        for (int i = 0; i < iters; ++i) {
            int q = i * 1024 + t;
            if (q < nq) {
                int b = 0;
                for (int j = 1; j < n_batch; ++j)
                    if (batch_off[j] <= q) b = j;
                b = min(b, 3);
                float rx = refp[q * 2 + 0], ry = refp[q * 2 + 1];
                int bx = min(15, max(0, (int)(rx * 16.f)));
                int by = min(15, max(0, (int)(ry * 16.f)));
                int bk = (b << 8) | (by << 4) | bx;
                bucket_of[q] = bk;
                atomicAdd(&cnt[bk], 1);
            }
        }
        __syncthreads();
        scan[t] = cnt[t];
        __syncthreads();
        for (int d = 1; d < NBK; d <<= 1) {
            int v = scan[t];
            int u = (t >= d) ? scan[t - d] : 0;
            __syncthreads();
            scan[t] = v + u;
            __syncthreads();
        }
        cnt[t] = scan[t] - cnt[t];
        __syncthreads();
        for (int i = 0; i < iters; ++i) {
            int q = i * 1024 + t;
            if (q < nq) {
                int bk = bucket_of[q];
                int pos = atomicAdd(&cnt[bk], 1);
                perm[pos] = q;
            }
        }
    }
}

// ------- K1: f16 2-pass MFMA GEMM: C = (Ah+Al) @ Bh^T + bias --------------
__global__ __launch_bounds__(256) void gemm_f16_kernel(
    const float*  __restrict__ A,     // (M,256) f32
    const __fp16* __restrict__ BT,    // (NTOT,256) f16
    const float* __restrict__ bias0,
    const float* __restrict__ bias1,
    float* __restrict__ C,
    int M, int NTOT, int bias_split)
{
    const int wave = threadIdx.x >> 6;
    const int lane = threadIdx.x & 63;
    const int gw   = blockIdx.x * 4 + wave;
    const int ngroups = NTOT >> 6;
    const int mg = gw / ngroups, ng = gw % ngroups;
    const int m16 = mg * 16, n64 = ng * 64;
    if (m16 >= M) return;

    const int mrow = lane & 15;
    const int quad = lane >> 4;

    const float4* Arow = (const float4*)(A + (size_t)(m16 + mrow) * 256 + quad * 8);
    const f16x8* B0 = (const f16x8*)(BT + (size_t)(n64 +  0 + mrow) * 256 + quad * 8);
    const f16x8* B1 = (const f16x8*)(BT + (size_t)(n64 + 16 + mrow) * 256 + quad * 8);
    const f16x8* B2 = (const f16x8*)(BT + (size_t)(n64 + 32 + mrow) * 256 + quad * 8);
    const f16x8* B3 = (const f16x8*)(BT + (size_t)(n64 + 48 + mrow) * 256 + quad * 8);

    f32x4 acc0 = {0.f,0.f,0.f,0.f}, acc1 = acc0, acc2 = acc0, acc3 = acc0;
    #pragma unroll
    for (int kb = 0; kb < 8; ++kb) {
        float4 a0 = Arow[kb * 8 + 0];
        float4 a1 = Arow[kb * 8 + 1];
        float av[8] = {a0.x, a0.y, a0.z, a0.w, a1.x, a1.y, a1.z, a1.w};
        f16x8 ah, al;
        #pragma unroll
        for (int j = 0; j < 8; ++j) {
            __fp16 h = (__fp16)av[j];
            ah[j] = h;
            al[j] = (__fp16)(av[j] - (float)h);
        }
        f16x8 b0 = B0[kb * 4], b1 = B1[kb * 4], b2 = B2[kb * 4], b3 = B3[kb * 4];
        acc0 = __builtin_amdgcn_mfma_f32_16x16x32_f16(ah, b0, acc0, 0, 0, 0);
        acc1 = __builtin_amdgcn_mfma_f32_16x16x32_f16(ah, b1, acc1, 0, 0, 0);
        acc2 = __builtin_amdgcn_mfma_f32_16x16x32_f16(ah, b2, acc2, 0, 0, 0);
        acc3 = __builtin_amdgcn_mfma_f32_16x16x32_f16(ah, b3, acc3, 0, 0, 0);
        acc0 = __builtin_amdgcn_mfma_f32_16x16x32_f16(al, b0, acc0, 0, 0, 0);
        acc1 = __builtin_amdgcn_mfma_f32_16x16x32_f16(al, b1, acc1, 0, 0, 0);
        acc2 = __builtin_amdgcn_mfma_f32_16x16x32_f16(al, b2, acc2, 0, 0, 0);
        acc3 = __builtin_amdgcn_mfma_f32_16x16x32_f16(al, b3, acc3, 0, 0, 0);
    }

    const int col = lane & 15;
    f32x4 accs[4] = {acc0, acc1, acc2, acc3};
    #pragma unroll
    for (int i = 0; i < 4; ++i) {
        int n = n64 + i * 16 + col;
        float b = (n < bias_split) ? bias0[n] : bias1[n - bias_split];
        #pragma unroll
        for (int r = 0; r < 4; ++r) {
            int row = m16 + quad * 4 + r;
            C[(size_t)row * NTOT + n] = accs[i][r] + b;
        }
    }
}

// ---------------- K3: plain f16 MFMA GEMM ---------------------------------
__global__ __launch_bounds__(256) void gemm_ff16_kernel(
    const __fp16* __restrict__ A,     // (M,256) f16
    const __fp16* __restrict__ BT,    // (NTOT,256) f16
    const float* __restrict__ bias,
    float* __restrict__ C,
    int M, int NTOT)
{
    const int wave = threadIdx.x >> 6;
    const int lane = threadIdx.x & 63;
    const int gw   = blockIdx.x * 4 + wave;
    const int ngroups = NTOT >> 6;
    const int mg = gw / ngroups, ng = gw % ngroups;
    const int m16 = mg * 16, n64 = ng * 64;
    if (m16 >= M) return;

    const int mrow = lane & 15;
    const int quad = lane >> 4;

    const f16x8* Arow = (const f16x8*)(A + (size_t)(m16 + mrow) * 256 + quad * 8);
    const f16x8* B0 = (const f16x8*)(BT + (size_t)(n64 +  0 + mrow) * 256 + quad * 8);
    const f16x8* B1 = (const f16x8*)(BT + (size_t)(n64 + 16 + mrow) * 256 + quad * 8);
    const f16x8* B2 = (const f16x8*)(BT + (size_t)(n64 + 32 + mrow) * 256 + quad * 8);
    const f16x8* B3 = (const f16x8*)(BT + (size_t)(n64 + 48 + mrow) * 256 + quad * 8);

    f32x4 acc0 = {0.f,0.f,0.f,0.f}, acc1 = acc0, acc2 = acc0, acc3 = acc0;
    #pragma unroll
    for (int kb = 0; kb < 8; ++kb) {
        f16x8 af = Arow[kb * 4];
        acc0 = __builtin_amdgcn_mfma_f32_16x16x32_f16(af, B0[kb * 4], acc0, 0, 0, 0);
        acc1 = __builtin_amdgcn_mfma_f32_16x16x32_f16(af, B1[kb * 4], acc1, 0, 0, 0);
        acc2 = __builtin_amdgcn_mfma_f32_16x16x32_f16(af, B2[kb * 4], acc2, 0, 0, 0);
        acc3 = __builtin_amdgcn_mfma_f32_16x16x32_f16(af, B3[kb * 4], acc3, 0, 0, 0);
    }

    const int col = lane & 15;
    f32x4 accs[4] = {acc0, acc1, acc2, acc3};
    #pragma unroll
    for (int i = 0; i < 4; ++i) {
        int n = n64 + i * 16 + col;
        float b = bias[n];
        #pragma unroll
        for (int r = 0; r < 4; ++r) {
            int row = m16 + quad * 4 + r;
            C[(size_t)row * NTOT + n] = accs[i][r] + b;
        }
    }
}

// ---------------- K2: softmax + sampling + bilinear gather (compact V) ----
__global__ __launch_bounds__(256) void msda_sample_kernel(
    const float*  __restrict__ refp,     // (Q, 2)
    const __fp16* __restrict__ Vc,       // compact f16 value tensor
    const float*  __restrict__ off_aw,   // (Q, 384)
    const int*    __restrict__ perm,     // (Q) locality-sorted ids
    const int*    __restrict__ batch_off,
    int n_batch,
    __fp16* __restrict__ out_pre,        // (Q, 256) f16
    int q_total)
{
    __shared__ int    sqid[QPB];
    __shared__ float  law[QPB][NC];
    __shared__ float2 sminv[QPB][NH];
    __shared__ float2 sref[QPB];
    __shared__ int4   soff[QPB][NC];
    __shared__ float4 swt[QPB][NC];

    const int t = threadIdx.x;
    const int chunk = gridDim.x >> 3;
    const int pblk  = (blockIdx.x & 7) * chunk + (blockIdx.x >> 3);
    const int q0 = pblk * QPB;

    if (t < QPB) sqid[t] = perm[q0 + t];
    __syncthreads();

    // ---- load attn logits ----
    {
        const int s = t >> 6, c = t & 63;
        const float* row = off_aw + (size_t)sqid[s] * NOFF_AW + ED;
        law[s][c]      = row[c];
        law[s][c + 64] = row[c + 64];
    }
    __syncthreads();

    // ---- softmax stats + ref-point prep ----
    if (t < QPB * NH) {
        const int s = t >> 3, h = t & 7;
        float m = -1e30f;
        #pragma unroll
        for (int lp = 0; lp < NLP; ++lp) m = fmaxf(m, law[s][lp * NH + h]);
        float sum = 0.f;
        #pragma unroll
        for (int lp = 0; lp < NLP; ++lp) sum += __expf(law[s][lp * NH + h] - m);
        sminv[s][h] = make_float2(m, 1.f / sum);
    } else if (t < QPB * NH + QPB) {
        const int s = t - QPB * NH;
        const int qid = sqid[s];
        float rx = refp[qid * 2 + 0], ry = refp[qid * 2 + 1];
        rx = fminf(fmaxf(rx, 0.f), 1.f);
        ry = fminf(fmaxf(ry, 0.f), 1.f);
        float ivx = __logf(fmaxf(rx, 1e-5f) / fmaxf(1.f - rx, 1e-5f));
        float ivy = __logf(fmaxf(ry, 1e-5f) / fmaxf(1.f - ry, 1e-5f));
        sref[s] = make_float2(ivx, ivy);
    }
    __syncthreads();

    // ---- sampling params (compact offsets): thread does c and c+64 ----
    {
        const int s = t >> 6;
        const int qid = sqid[s];
        int b = 0;
        for (int i = 1; i < n_batch; ++i)
            if (batch_off[i] <= qid) b = i;
        const int cb = b * PBC;
        const float2 iv = sref[s];
        const float* offrow = off_aw + (size_t)qid * NOFF_AW;

        #pragma unroll
        for (int half = 0; half < 2; ++half) {
            const int c = (t & 63) + half * 64;
            const int l = c >> 5;
            const int h = c & 7;
            const int lsh = 7 - l;            // log2(level size)
            const int sz  = 1 << lsh;
            const int cap = sz - 1;

            const float2 mi = sminv[s][h];
            const float a = __expf(law[s][c] - mi.x) * mi.y;

            const float ox = offrow[c * 2 + 0], oy = offrow[c * 2 + 1];
            float lx = 2.f / (1.f + __expf(-(iv.x + ox))) - 1.f;
            float ly = 2.f / (1.f + __expf(-(iv.y + oy))) - 1.f;
            float x = ((lx + 1.f) * (float)sz - 1.f) * 0.5f;
            float y = ((ly + 1.f) * (float)sz - 1.f) * 0.5f;
            int x0 = (int)floorf(x), y0 = (int)floorf(y);
            int x1 = x0 + 1, y1 = y0 + 1;
            x0 = min(max(x0, 0), cap); x1 = min(max(x1, 0), cap);
            y0 = min(max(y0, 0), cap); y1 = min(max(y1, 0), cap);
            float x0f = (float)x0, x1f = (float)x1;
            float y0f = (float)y0, y1f = (float)y1;

            float4 w;
            w.x = a * (x1f - x) * (y1f - y);
            w.y = a * (x1f - x) * (y - y0f);
            w.z = a * (x - x0f) * (y1f - y);
            w.w = a * (x - x0f) * (y - y0f);
            swt[s][c] = w;
            const int lb = cb + (LBASE_ROW[l] << 8);
            int4 o;
            o.x = lb + (((x0 << lsh) + y0) << 8);
            o.y = lb + (((x0 << lsh) + y1) << 8);
            o.z = lb + (((x1 << lsh) + y0) << 8);
            o.w = lb + (((x1 << lsh) + y1) << 8);
            soff[s][c] = o;
        }
    }
    __syncthreads();

    // ---- gather: one wave per query; lane = (h, d4); f16x4 corners ----
    {
        const int s    = t >> 6;
        const int lane = t & 63;
        const int h    = lane >> 3;
        const int d4   = (lane & 7) << 2;
        const int inner = h * HD + d4;
        float4 acc = {0.f, 0.f, 0.f, 0.f};
        #pragma unroll 4
        for (int lp = 0; lp < NLP; ++lp) {
            const int c = lp * NH + h;
            int4   o = soff[s][c];
            float4 w = swt[s][c];
            f16x4 v0 = *(const f16x4*)&Vc[o.x + inner];
            f16x4 v1 = *(const f16x4*)&Vc[o.y + inner];
            f16x4 v2 = *(const f16x4*)&Vc[o.z + inner];
            f16x4 v3 = *(const f16x4*)&Vc[o.w + inner];
            acc.x += w.x*(float)v0[0] + w.y*(float)v1[0] + w.z*(float)v2[0] + w.w*(float)v3[0];
            acc.y += w.x*(float)v0[1] + w.y*(float)v1[1] + w.z*(float)v2[1] + w.w*(float)v3[1];
            acc.z += w.x*(float)v0[2] + w.y*(float)v1[2] + w.z*(float)v2[2] + w.w*(float)v3[2];
            acc.w += w.x*(float)v0[3] + w.y*(float)v1[3] + w.z*(float)v2[3] + w.w*(float)v3[3];
        }
        f16x4 o4;
        o4[0] = (__fp16)acc.x; o4[1] = (__fp16)acc.y;
        o4[2] = (__fp16)acc.z; o4[3] = (__fp16)acc.w;
        *(f16x4*)&out_pre[(size_t)sqid[s] * ED + inner] = o4;
    }
}

extern "C" void kernel_launch(void* const* d_in, const int* in_sizes, int n_in,
                              void* d_out, int out_size, void* d_ws, size_t ws_size,
                              hipStream_t stream) {
    const float* query  = (const float*)d_in[0];
    const float* refp   = (const float*)d_in[1];
    const float* V      = (const float*)d_in[2];
    const float* W_off  = (const float*)d_in[3];
    const float* b_off  = (const float*)d_in[4];
    const float* W_attn = (const float*)d_in[5];
    const float* b_attn = (const float*)d_in[6];
    const float* W_out  = (const float*)d_in[7];
    const float* b_out  = (const float*)d_in[8];
    const int*   boff   = (const int*)d_in[9];
    const int*   spat   = (const int*)d_in[10];
    const int n_batch   = in_sizes[9];
    const int nq        = in_sizes[0] / ED;
    const int nb        = in_sizes[2] / BSTRIDE;
    float* out = (float*)d_out;

    // workspace layout (all chunks 16B-aligned)
    char* ws = (char*)d_ws;
    float*   off_aw    = (float*)ws;                             // nq*384 f32
    int*     perm      = (int*)(off_aw + (size_t)nq * NOFF_AW);  // nq int
    int*     bucket_of = perm + nq;                              // nq int
    __fp16*  WcatT     = (__fp16*)(bucket_of + nq);              // 384*256 f16
    __fp16*  WoutT     = WcatT + NOFF_AW * ED;                   // 256*256 f16
    __fp16*  out_pre   = WoutT + ED * ED;                        // nq*256 f16
    __fp16*  Vc        = out_pre + (size_t)nq * ED;              // nb*RPB*256 f16

    // Kprep: V compaction + weight conversion + locality sort
    {
        int nCompact = (nb * RPB + 15) / 16;
        int nWconv   = (NOFF_AW * ED + ED * ED + 1023) / 1024;
        msda_prep_kernel<<<nCompact + nWconv + 1, 1024, 0, stream>>>(
            V, W_off, W_attn, W_out, refp, boff, n_batch,
            Vc, WcatT, WoutT, bucket_of, perm, nq, nb, nCompact, nWconv);
    }
    // K1: [off|aw] = q @ [W_off|W_attn] + bias  (f16 2-pass, A exact)
    {
        int waves = (nq / 16) * (NOFF_AW / 64);
        gemm_f16_kernel<<<(waves + 3) / 4, 256, 0, stream>>>(
            query, WcatT, b_off, b_attn, off_aw, nq, NOFF_AW, ED);
    }
    // K2: sampling + gather (compact f16 V) -> out_pre (f16)
    {
        msda_sample_kernel<<<nq / QPB, 256, 0, stream>>>(
            refp, Vc, off_aw, perm, boff, n_batch, out_pre, nq);
    }
    // K3: out = out_pre @ W_out + b_out
    {
        int waves = (nq / 16) * (ED / 64);
        gemm_ff16_kernel<<<(waves + 3) / 4, 256, 0, stream>>>(
            out_pre, WoutT, b_out, out, nq, ED);
    }
}